// Round 6
// baseline (483.458 us; speedup 1.0000x reference)
//
#include <hip/hip_runtime.h>
#include <hip/hip_bf16.h>
#include <stdint.h>

// ---------------------------------------------------------------------------
// Self-attention forward, B=4 S=4096 D=1024, fp32 in -> f32 out.
// GEMM: 256x256 tile, BK=64, 8 waves. kh-split phases with counted vmcnt(4)
// (never 0 mid-loop), kh-major LDS w/ XOR slot swizzle (conflict-free b128),
// one barrier per phase, setprio, XCD-chunked block swizzle.
// ---------------------------------------------------------------------------

typedef __attribute__((ext_vector_type(8))) short bf16x8;
typedef __attribute__((ext_vector_type(4))) float f32x4;

static __device__ __forceinline__ unsigned short f2b(float f) {
  union { float f; unsigned u; } x; x.f = f;
  unsigned u = x.u;
  u += 0x7fffu + ((u >> 16) & 1u);      // RNE
  return (unsigned short)(u >> 16);
}
static __device__ __forceinline__ float b2f(unsigned short s) {
  union { unsigned u; float f; } x; x.u = ((unsigned)s) << 16;
  return x.f;
}

// async global->LDS, 16B per lane. LDS dest: wave-uniform base + lane*16.
static __device__ __forceinline__ void gl_lds16(const void* g, void* l) {
  __builtin_amdgcn_global_load_lds(
      (const __attribute__((address_space(1))) void*)(uintptr_t)(g),
      (__attribute__((address_space(3))) void*)(uint32_t)(uintptr_t)(l),
      16, 0, 0);
}

// ---------------------------------------------------------------------------
__global__ void convert_x(const float* __restrict__ in,
                          unsigned short* __restrict__ out, int n8) {
  int i = blockIdx.x * blockDim.x + threadIdx.x;
  if (i >= n8) return;
  const float4* p = (const float4*)in + (size_t)i * 2;
  float4 a = p[0], b = p[1];
  bf16x8 o;
  o[0] = (short)f2b(a.x); o[1] = (short)f2b(a.y);
  o[2] = (short)f2b(a.z); o[3] = (short)f2b(a.w);
  o[4] = (short)f2b(b.x); o[5] = (short)f2b(b.y);
  o[6] = (short)f2b(b.z); o[7] = (short)f2b(b.w);
  ((bf16x8*)out)[i] = o;
}

__global__ void transpose_w(const float* __restrict__ in,
                            unsigned short* __restrict__ out) {
  __shared__ float tile[32][33];
  const int tx = threadIdx.x;
  const int x = blockIdx.x * 32 + tx;
  const int y0 = blockIdx.y * 32;
  for (int j = threadIdx.y; j < 32; j += 8)
    tile[j][tx] = in[(size_t)(y0 + j) * 1024 + x];
  __syncthreads();
  const int ox = blockIdx.y * 32 + tx;
  const int oy0 = blockIdx.x * 32;
  for (int j = threadIdx.y; j < 32; j += 8)
    out[(size_t)(oy0 + j) * 1024 + ox] = f2b(tile[tx][j]);
}

// ---------------------------------------------------------------------------
// 256x256 NT GEMM, BK=64, 512 threads (8 waves, 2x4), dbuf LDS (kh-major).
// C[m][n] = alpha * sum_k A[m][k]*B[n][k] (+bias). z-batched via strides.
// Requires M%256==0, N%256==0, K%64==0, K/64>=2.
//
// LDS region (buf,kh) = [256 rows][32 k] bf16, 16KB. Slot map within a row
// (4 slots of 16B): slot = oct ^ ((row>>1)&3). Stage side writes linearly
// (gl_lds) from a pre-permuted global source; read side applies the same
// map => bijective, and b128 reads hit each bank-quad exactly 8x (no
// conflicts).
// ---------------------------------------------------------------------------
template <int OUTF>
__global__ __launch_bounds__(512, 2)
void gemm256(const unsigned short* __restrict__ A, long lda, long sAz,
             const unsigned short* __restrict__ B, long ldb, long sBz,
             void* __restrict__ Cv, long ldc, long sCz,
             const float* __restrict__ bias, int bias_mode,
             int K, float alpha) {
  __shared__ __align__(16) unsigned short As[2][2][8192];
  __shared__ __align__(16) unsigned short Bs[2][2][8192];

  // XCD-chunked block swizzle (T1)
  const unsigned gx = gridDim.x, gy = gridDim.y;
  const unsigned nwg = gx * gy * gridDim.z;
  const unsigned hwid = (blockIdx.z * gy + blockIdx.y) * gx + blockIdx.x;
  unsigned tile = hwid;
  if ((nwg & 7u) == 0u) tile = (hwid & 7u) * (nwg >> 3) + (hwid >> 3);
  const unsigned bxi = tile % gx;
  const unsigned byi = (tile / gx) % gy;
  const unsigned bzi = tile / (gx * gy);

  const int t = threadIdx.x;
  const int wid = t >> 6, lane = t & 63;
  const int wm = wid >> 2, wn = wid & 3;      // 2x4 wave grid
  const int fr = lane & 15, fq = lane >> 4;
  const long bm = (long)byi * 256;
  const long bn = (long)bxi * 256;
  const unsigned short* Ab = A + (size_t)bzi * sAz;
  const unsigned short* Bb = B + (size_t)bzi * sBz;

  // ---- staging maps (per-thread constants) ----
  const int srow = t >> 2;                             // 0..127
  const int soct8 = (((t & 3) ^ ((t >> 3) & 3))) * 8;  // permuted octet
  const unsigned short* AgS = Ab + (bm + srow) * lda + soct8;
  const unsigned short* BgS = Bb + (bn + srow) * ldb + soct8;
  const int dstw = wid * 512;                          // shorts within region
  // ---- read map ----
  const int rs16 = (fq ^ ((fr >> 1) & 3)) << 4;        // slot byte offset

  const int NT = K >> 6;
  f32x4 acc[8][4] = {};

  auto stg = [&](const unsigned short* GS, long ld, unsigned short* region,
                 int kt, int kh) {
    const unsigned short* s0 = GS + (size_t)kt * 64 + kh * 32;
    gl_lds16(s0, region + dstw);
    gl_lds16(s0 + (size_t)128 * ld, region + 4096 + dstw);
  };
  auto rdA = [&](int buf, int kh, int i) {
    return *(const bf16x8*)((const char*)&As[buf][kh][0] +
                            (wm * 128 + i * 16 + fr) * 64 + rs16);
  };
  auto rdB = [&](int buf, int kh, int j) {
    return *(const bf16x8*)((const char*)&Bs[buf][kh][0] +
                            (wn * 64 + j * 16 + fr) * 64 + rs16);
  };

  // prologue: stage tile0 kh0 (4 loads), then kh1 (4 loads); wait kh0 only.
  stg(AgS, lda, &As[0][0][0], 0, 0); stg(BgS, ldb, &Bs[0][0][0], 0, 0);
  stg(AgS, lda, &As[0][1][0], 0, 1); stg(BgS, ldb, &Bs[0][1][0], 0, 1);
  asm volatile("s_waitcnt vmcnt(4)" ::: "memory");
  asm volatile("s_barrier" ::: "memory");

#define PHASE(kh)                                                             \
  do {                                                                        \
    if (tt + 1 < NT) {                                                        \
      stg(AgS, lda, &As[nb][kh][0], tt + 1, kh);                              \
      stg(BgS, ldb, &Bs[nb][kh][0], tt + 1, kh);                              \
    }                                                                         \
    bf16x8 bfr[4], ar[2], arn[2];                                             \
    _Pragma("unroll")                                                         \
    for (int j = 0; j < 4; ++j) bfr[j] = rdB(cb, kh, j);                      \
    ar[0] = rdA(cb, kh, 0); ar[1] = rdA(cb, kh, 1);                           \
    __builtin_amdgcn_s_setprio(1);                                            \
    _Pragma("unroll")                                                         \
    for (int p = 0; p < 4; ++p) {                                             \
      if (p < 3) {                                                            \
        arn[0] = rdA(cb, kh, p * 2 + 2);                                      \
        arn[1] = rdA(cb, kh, p * 2 + 3);                                      \
      }                                                                       \
      _Pragma("unroll")                                                       \
      for (int ii = 0; ii < 2; ++ii)                                          \
        _Pragma("unroll")                                                     \
        for (int j = 0; j < 4; ++j)                                           \
          acc[p * 2 + ii][j] = __builtin_amdgcn_mfma_f32_16x16x32_bf16(       \
              ar[ii], bfr[j], acc[p * 2 + ii][j], 0, 0, 0);                   \
      if (p < 3) { ar[0] = arn[0]; ar[1] = arn[1]; }                          \
    }                                                                         \
    __builtin_amdgcn_s_setprio(0);                                            \
  } while (0)

  for (int tt = 0; tt < NT; ++tt) {
    const int cb = tt & 1, nb = (tt + 1) & 1;
    // phase kh=0 (tt==0: prologue already waited+synced)
    if (tt > 0) {
      asm volatile("s_waitcnt vmcnt(4)" ::: "memory");
      asm volatile("s_barrier" ::: "memory");
    }
    PHASE(0);
    // phase kh=1
    if (tt + 1 < NT) {
      asm volatile("s_waitcnt vmcnt(4)" ::: "memory");
    } else {
      asm volatile("s_waitcnt vmcnt(0)" ::: "memory");
    }
    asm volatile("s_barrier" ::: "memory");
    PHASE(1);
  }
#undef PHASE

  // epilogue: C/D layout col=lane&15, row=(lane>>4)*4+reg  [m89/m91]
  char* Cb = (char*)Cv + (size_t)bzi * sCz * (OUTF ? 4 : 2);
  const long crow0 = bm + wm * 128 + fq * 4;
  const long ccol0 = bn + wn * 64 + fr;
#pragma unroll
  for (int i = 0; i < 8; ++i) {
#pragma unroll
    for (int j = 0; j < 4; ++j) {
      const long col = ccol0 + j * 16;
      float badd_c = (bias_mode == 1) ? bias[col] : 0.0f;
#pragma unroll
      for (int r = 0; r < 4; ++r) {
        const long row = crow0 + i * 16 + r;
        float v = acc[i][j][r] * alpha + badd_c;
        if (bias_mode == 2) v += bias[row];
        if (OUTF)
          ((float*)Cb)[row * ldc + col] = v;
        else
          ((unsigned short*)Cb)[row * ldc + col] = f2b(v);
      }
    }
  }
}

// ---------------------------------------------------------------------------
// In-place row softmax over bf16 rows of length 4096. One block (256thr)/row.
// ---------------------------------------------------------------------------
__global__ __launch_bounds__(256)
void softmax_rows(unsigned short* __restrict__ S) {
  const int t = threadIdx.x;
  unsigned short* row = S + (size_t)blockIdx.x * 4096;
  const bf16x8* p = (const bf16x8*)row;
  bf16x8 u0 = p[t * 2], u1 = p[t * 2 + 1];

  float v[16];
  float m = -1e30f;
#pragma unroll
  for (int j = 0; j < 8; j++) { v[j] = b2f((unsigned short)u0[j]); }
#pragma unroll
  for (int j = 0; j < 8; j++) { v[8 + j] = b2f((unsigned short)u1[j]); }
#pragma unroll
  for (int j = 0; j < 16; j++) m = fmaxf(m, v[j]);

#pragma unroll
  for (int off = 32; off > 0; off >>= 1) m = fmaxf(m, __shfl_xor(m, off));
  __shared__ float redm[4];
  if ((t & 63) == 0) redm[t >> 6] = m;
  __syncthreads();
  m = fmaxf(fmaxf(redm[0], redm[1]), fmaxf(redm[2], redm[3]));

  float s = 0.0f;
#pragma unroll
  for (int j = 0; j < 16; j++) { v[j] = __expf(v[j] - m); s += v[j]; }
#pragma unroll
  for (int off = 32; off > 0; off >>= 1) s += __shfl_xor(s, off);
  __shared__ float reds[4];
  if ((t & 63) == 0) reds[t >> 6] = s;
  __syncthreads();
  s = reds[0] + reds[1] + reds[2] + reds[3];
  const float inv = 1.0f / s;

  bf16x8 o0, o1;
#pragma unroll
  for (int j = 0; j < 8; j++) o0[j] = (short)f2b(v[j] * inv);
#pragma unroll
  for (int j = 0; j < 8; j++) o1[j] = (short)f2b(v[8 + j] * inv);
  bf16x8* q = (bf16x8*)row;
  q[t * 2] = o0;
  q[t * 2 + 1] = o1;
}

// ---------------------------------------------------------------------------
extern "C" void kernel_launch(void* const* d_in, const int* in_sizes, int n_in,
                              void* d_out, int out_size, void* d_ws,
                              size_t ws_size, hipStream_t stream) {
  const float* x  = (const float*)d_in[0];
  const float* Wq = (const float*)d_in[1];
  const float* bq = (const float*)d_in[2];
  const float* Wk = (const float*)d_in[3];
  const float* bk = (const float*)d_in[4];
  const float* Wv = (const float*)d_in[5];
  const float* bv = (const float*)d_in[6];
  float* out = (float*)d_out;

  const int Bb = 4, S = 4096, D = 1024;
  const long BS = (long)Bb * S;                 // 16384
  const size_t MiB = 1u << 20;

  char* base = (char*)d_ws;
  unsigned short* Wqt = (unsigned short*)(base);              // 2 MiB
  unsigned short* Wkt = (unsigned short*)(base + 2 * MiB);    // 2
  unsigned short* Wvt = (unsigned short*)(base + 4 * MiB);    // 2
  unsigned short* Qb  = (unsigned short*)(base + 6 * MiB);    // 32
  unsigned short* Kb  = (unsigned short*)(base + 38 * MiB);   // 32
  unsigned short* Vt  = (unsigned short*)(base + 70 * MiB);   // 32  [D][BS]
  unsigned short* xb  = (unsigned short*)(base + 102 * MiB);  // 32 (dies early)
  unsigned short* Sb  = xb;  // scores region overlaps dead xb
  const bool batched = ws_size >= (size_t)(102 + 128) * MiB;  // 4-batch scores

  // 1. x -> bf16
  const int n8 = (int)(BS * D / 8);
  convert_x<<<n8 / 256, 256, 0, stream>>>(x, xb, n8);

  // 2. W -> W^T bf16
  dim3 tb(32, 8), tg(32, 32);
  transpose_w<<<tg, tb, 0, stream>>>(Wq, Wqt);
  transpose_w<<<tg, tb, 0, stream>>>(Wk, Wkt);
  transpose_w<<<tg, tb, 0, stream>>>(Wv, Wvt);

  // 3. projections
  gemm256<0><<<dim3(D / 256, BS / 256, 1), 512, 0, stream>>>(
      xb, D, 0, Wqt, D, 0, Qb, D, 0, bq, 1, D, 1.0f);
  gemm256<0><<<dim3(D / 256, BS / 256, 1), 512, 0, stream>>>(
      xb, D, 0, Wkt, D, 0, Kb, D, 0, bk, 1, D, 1.0f);
  gemm256<0><<<dim3(BS / 256, D / 256, 1), 512, 0, stream>>>(
      Wvt, D, 0, xb, D, 0, Vt, BS, 0, bv, 2, D, 1.0f);

  // 4. attention
  const float scale = 0.03125f;  // 1/sqrt(1024)
  if (batched) {
    gemm256<0><<<dim3(S / 256, S / 256, Bb), 512, 0, stream>>>(
        Qb, D, (long)S * D, Kb, D, (long)S * D, Sb, S, (long)S * S,
        nullptr, 0, D, scale);
    softmax_rows<<<Bb * S, 256, 0, stream>>>(Sb);
    gemm256<1><<<dim3(D / 256, S / 256, Bb), 512, 0, stream>>>(
        Sb, S, (long)S * S, Vt, BS, (long)S, out, D, (long)S * D,
        nullptr, 0, S, 1.0f);
  } else {
    for (int b = 0; b < Bb; b++) {
      const unsigned short* Qp = Qb + (long)b * S * D;
      const unsigned short* Kp = Kb + (long)b * S * D;
      gemm256<0><<<dim3(S / 256, S / 256, 1), 512, 0, stream>>>(
          Qp, D, 0, Kp, D, 0, Sb, S, 0, nullptr, 0, D, scale);
      softmax_rows<<<S, 256, 0, stream>>>(Sb);
      gemm256<1><<<dim3(D / 256, S / 256, 1), 512, 0, stream>>>(
          Sb, S, 0, Vt + (long)b * S, BS, 0, out + (long)b * S * D, D, 0,
          nullptr, 0, S, 1.0f);
    }
  }
}